// Round 15
// baseline (8862.692 us; speedup 1.0000x reference)
//
#include <hip/hip_runtime.h>

// LSTM on MI355X — persistent kernel, round 14.
// Base = R13 (4272us). Structural change: FLAG LAYER DELETED -> sentinel
// dataflow. Ring pre-poisoned with bf16 NaN (0xFFFF) each call (write-once +
// h in [-1,1] => sentinel unambiguous). Producers publish (sc0sc1) with NO
// drain/flag/counter; consumers pre-issue sc1 chunk loads and poll the DATA
// (dword 0/2 vs sentinel), retrying only invalid chunks with s_sleep backoff.
// No __syncthreads in the main loop: per-wave epilogue + publish, 1024 waves
// fully decoupled. Numerics identical. absmax canary: 0.001953125.

namespace {
constexpr int T_STEPS = 512;
constexpr int BATCH   = 64;
constexpr int DI      = 512;
constexpr int DL      = 1024;
constexpr int NKC     = 48;   // K=1536 in chunks of 32
constexpr int NKC_H   = 32;   // h-part chunks (K=1024)
constexpr int NBLK    = 256;  // grid == CU count, 1 block/CU (80KB LDS forces it)
constexpr int NTHR    = 256;  // 4 compute waves, fully decoupled
constexpr unsigned SENT = 0xFFFFFFFFu;   // two bf16 NaNs
}

typedef __attribute__((ext_vector_type(8))) short bf16x8;
typedef __attribute__((ext_vector_type(8))) unsigned short u16x8;
typedef __attribute__((ext_vector_type(4))) float f32x4;
typedef __attribute__((ext_vector_type(4))) unsigned int u32x4;
typedef __attribute__((ext_vector_type(2))) unsigned int u32x2;

__device__ __forceinline__ unsigned short f2bf(float x){
  unsigned int u = __float_as_uint(x);
  return (unsigned short)((u + 0x7FFFu + ((u >> 16) & 1u)) >> 16);
}
__device__ __forceinline__ float bf2f(unsigned short b){
  return __uint_as_float(((unsigned int)b) << 16);
}
__device__ __forceinline__ float fast_sigmoid(float v){
  return __fdividef(1.f, 1.f + __expf(-v));
}
__device__ __forceinline__ float fast_tanh(float v){
  v = fminf(fmaxf(v, -15.f), 15.f);
  float t = __expf(2.f * v);
  return __fdividef(t - 1.f, t + 1.f);
}

// ---------------- prep: poison ring with sentinel (write-once guarantee) ----------------
__global__ void prep_ring(u32x4* __restrict__ dst, int n16){
  int i = blockIdx.x * blockDim.x + threadIdx.x;
  if (i < n16) dst[i] = (u32x4){SENT, SENT, SENT, SENT};
}

// ---------------- prep: embeddings -> bf16 [T*B][DI] ----------------
__global__ void prep_xe(const int* __restrict__ X, const float* __restrict__ emb,
                        unsigned short* __restrict__ xe){
  int i = blockIdx.x * blockDim.x + threadIdx.x;
  const int total = T_STEPS * BATCH * DI / 8;
  if (i >= total) return;
  int row = i >> 6;
  int seg = i & 63;
  int tok = X[row];
  const float* src = emb + (long long)tok * DI + seg * 8;
  float4 v0 = *(const float4*)src;
  float4 v1 = *(const float4*)(src + 4);
  u16x8 o;
  o[0]=f2bf(v0.x); o[1]=f2bf(v0.y); o[2]=f2bf(v0.z); o[3]=f2bf(v0.w);
  o[4]=f2bf(v1.x); o[5]=f2bf(v1.y); o[6]=f2bf(v1.z); o[7]=f2bf(v1.w);
  *(u16x8*)(xe + (long long)row * DI + seg * 8) = o;
}

// ---------------- prep: pack W into MFMA B-fragment layout, hi/lo ----------------
__global__ void prep_w(const float* __restrict__ Wf, const float* __restrict__ Wi,
                       const float* __restrict__ Wc, const float* __restrict__ Wo,
                       unsigned short* __restrict__ W_hi, unsigned short* __restrict__ W_lo){
  int idx = blockIdx.x * blockDim.x + threadIdx.x;
  if (idx >= 256 * NKC * 64) return;
  int lane = idx & 63;
  int kc   = (idx >> 6) % NKC;
  int bk   = idx / (64 * NKC);
  int lc = lane & 15, kg = lane >> 4;
  int g  = lc >> 2;
  int jl = bk * 4 + (lc & 3);
  const float* Wg = (g == 0) ? Wf : ((g == 1) ? Wi : ((g == 2) ? Wc : Wo));
  int kbase = kc * 32 + kg * 8;
  u16x8 hi, lo;
#pragma unroll
  for (int j = 0; j < 8; j++){
    float wv = Wg[(long long)(kbase + j) * DL + jl];
    unsigned short h = f2bf(wv);
    hi[j] = h;
    lo[j] = f2bf(wv - bf2f(h));
  }
  *(u16x8*)(W_hi + ((long long)(bk * NKC + kc) * 64 + lane) * 8) = hi;
  if (kc < NKC_H)
    *(u16x8*)(W_lo + ((long long)(bk * NKC_H + kc) * 64 + lane) * 8) = lo;
}

// ---------------- prep: h0 -> ring slot 0 (bf16), bias pack ----------------
__global__ void prep_h(const float* __restrict__ h0,
                       const float* __restrict__ bf_, const float* __restrict__ bi_,
                       const float* __restrict__ bc_, const float* __restrict__ bo_,
                       unsigned short* __restrict__ hRing,
                       float* __restrict__ bias_pack){
  int i = blockIdx.x * blockDim.x + threadIdx.x;
  if (i < BATCH * DL) hRing[i] = f2bf(h0[i]);      // slot 0 = h_0 (overwrites poison)
  if (i < 4096){
    int r = i & 3, g = (i >> 2) & 3, bk = i >> 4;
    const float* bg = (g == 0) ? bf_ : ((g == 1) ? bi_ : ((g == 2) ? bc_ : bo_));
    bias_pack[i] = bg[bk * 4 + r];
  }
}

// ---------------- persistent LSTM: all 512 steps, sentinel dataflow ----------------
__launch_bounds__(NTHR, 1)
__global__ void lstm_persist(const unsigned short* __restrict__ xe,
                             const unsigned short* __restrict__ W_hi,
                             const unsigned short* __restrict__ W_lo,
                             unsigned short* __restrict__ hRing,   // [T+1][B*DL]
                             const float* __restrict__ bias_pack,
                             float* __restrict__ out){
  extern __shared__ unsigned short lds[];
  unsigned short* lds_hi = lds;              // NKC  *512 elems (48 KB)
  unsigned short* lds_lo = lds + NKC * 512;  // NKC_H*512 elems (32 KB)
  __shared__ __align__(8)  unsigned short sh_h[4][64];  // per-wave h stage (bf16)
  __shared__ __align__(16) float          sh_o[4][64];  // per-wave out stage
  const int tid  = threadIdx.x;
  const int bk   = blockIdx.x;
  const int w    = tid >> 6;
  const int lane = tid & 63;

  // stage W once for the whole run (only __syncthreads in the kernel)
  const uint4* srcHi = (const uint4*)(W_hi + (size_t)bk * NKC * 512);
  uint4* dHi = (uint4*)lds_hi;
  for (int i = tid; i < 3072; i += NTHR) dHi[i] = srcHi[i];
  const uint4* srcLo = (const uint4*)(W_lo + (size_t)bk * NKC_H * 512);
  uint4* dLo = (uint4*)lds_lo;
  for (int i = tid; i < 2048; i += NTHR) dLo[i] = srcLo[i];
  __syncthreads();

  const int lc = lane & 15;
  const int kg = lane >> 4;
  const int g  = lc >> 2;
  const int rowb = (w << 4) + lc;
  const float bias = bias_pack[bk * 16 + lc];
  const int srcBase = (lane & 48) | (lc & 3);
  const int hOff = rowb * DL + kg * 8;     // u16 elements
  const int xOff = rowb * DI + kg * 8;
  float cr0 = 0.f, cr1 = 0.f, cr2 = 0.f, cr3 = 0.f;

  f32x4 acc0 = {0.f,0.f,0.f,0.f}, acc1 = {0.f,0.f,0.f,0.f};
  f32x4 acc2 = {0.f,0.f,0.f,0.f}, acc3 = {0.f,0.f,0.f,0.f};
  u32x4 hv[32];

#define XSTEP(KC, ACC) {                                                        \
    bf16x8 ax = *(const bf16x8*)(xRow + (KC) * 32);                             \
    bf16x8 bh = *(const bf16x8*)(lds_hi + (NKC_H + (KC)) * 512 + lane * 8);     \
    ACC = __builtin_amdgcn_mfma_f32_16x16x32_bf16(ax, bh, ACC, 0, 0, 0); }
#define HSTEP2(KC, ACC) {                                                       \
    bf16x8 ah = *(const bf16x8*)&hv[KC];                                        \
    bf16x8 bh = *(const bf16x8*)(lds_hi + (KC) * 512 + lane * 8);               \
    bf16x8 bl = *(const bf16x8*)(lds_lo + (KC) * 512 + lane * 8);               \
    ACC = __builtin_amdgcn_mfma_f32_16x16x32_bf16(ah, bh, ACC, 0, 0, 0);        \
    ACC = __builtin_amdgcn_mfma_f32_16x16x32_bf16(ah, bl, ACC, 0, 0, 0); }
#define LOADHU(I, OFFSTR)                                                       \
    asm volatile("global_load_dwordx4 %0, %1, off offset:" OFFSTR " sc0 sc1"    \
                 : "=v"(hv[I]) : "v"(hbase));
#define ISSUE_ALL                                                               \
    LOADHU( 0,"0")    LOADHU( 1,"64")   LOADHU( 2,"128")  LOADHU( 3,"192")     \
    LOADHU( 4,"256")  LOADHU( 5,"320")  LOADHU( 6,"384")  LOADHU( 7,"448")     \
    LOADHU( 8,"512")  LOADHU( 9,"576")  LOADHU(10,"640")  LOADHU(11,"704")     \
    LOADHU(12,"768")  LOADHU(13,"832")  LOADHU(14,"896")  LOADHU(15,"960")     \
    LOADHU(16,"1024") LOADHU(17,"1088") LOADHU(18,"1152") LOADHU(19,"1216")    \
    LOADHU(20,"1280") LOADHU(21,"1344") LOADHU(22,"1408") LOADHU(23,"1472")    \
    LOADHU(24,"1536") LOADHU(25,"1600") LOADHU(26,"1664") LOADHU(27,"1728")    \
    LOADHU(28,"1792") LOADHU(29,"1856") LOADHU(30,"1920") LOADHU(31,"1984")
#define CHK(KC) { int bad = (hv[KC][0] == SENT) | (hv[KC][2] == SENT);          \
                  if (__any(bad)) inval |= (1u << (KC)); }
#define RLD(KC, OFFSTR) if (inval & (1u << (KC))) { LOADHU(KC, OFFSTR) }
#define RCK(KC) if (inval & (1u << (KC))) {                                     \
                  int bad = (hv[KC][0] == SENT) | (hv[KC][2] == SENT);          \
                  if (!__any(bad)) inval &= ~(1u << (KC)); }

  // prologue: issue slot-0 loads + x-part(0)
  {
    const unsigned short* hbase = hRing + hOff;
    ISSUE_ALL
    const unsigned short* xRow = xe + xOff;
#pragma unroll
    for (int kc = 0; kc < 16; kc += 4){
      XSTEP(kc, acc0) XSTEP(kc + 1, acc1) XSTEP(kc + 2, acc2) XSTEP(kc + 3, acc3)
    }
  }

#pragma unroll 1
  for (int t = 0; t < T_STEPS; ++t){
    // ---- wait loads, sentinel-validate, retry invalid chunks ----
    asm volatile("s_waitcnt vmcnt(0)" ::: "memory");
    __builtin_amdgcn_sched_barrier(0);
    unsigned inval = 0u;
    CHK( 0) CHK( 1) CHK( 2) CHK( 3) CHK( 4) CHK( 5) CHK( 6) CHK( 7)
    CHK( 8) CHK( 9) CHK(10) CHK(11) CHK(12) CHK(13) CHK(14) CHK(15)
    CHK(16) CHK(17) CHK(18) CHK(19) CHK(20) CHK(21) CHK(22) CHK(23)
    CHK(24) CHK(25) CHK(26) CHK(27) CHK(28) CHK(29) CHK(30) CHK(31)
    if (inval){
      const unsigned short* hbase = hRing + (size_t)t * (BATCH * DL) + hOff;
      int spin = 0;
      do {
        __builtin_amdgcn_s_sleep(1);
        RLD( 0,"0")    RLD( 1,"64")   RLD( 2,"128")  RLD( 3,"192")
        RLD( 4,"256")  RLD( 5,"320")  RLD( 6,"384")  RLD( 7,"448")
        RLD( 8,"512")  RLD( 9,"576")  RLD(10,"640")  RLD(11,"704")
        RLD(12,"768")  RLD(13,"832")  RLD(14,"896")  RLD(15,"960")
        RLD(16,"1024") RLD(17,"1088") RLD(18,"1152") RLD(19,"1216")
        RLD(20,"1280") RLD(21,"1344") RLD(22,"1408") RLD(23,"1472")
        RLD(24,"1536") RLD(25,"1600") RLD(26,"1664") RLD(27,"1728")
        RLD(28,"1792") RLD(29,"1856") RLD(30,"1920") RLD(31,"1984")
        asm volatile("s_waitcnt vmcnt(0)" ::: "memory");
        __builtin_amdgcn_sched_barrier(0);
        RCK( 0) RCK( 1) RCK( 2) RCK( 3) RCK( 4) RCK( 5) RCK( 6) RCK( 7)
        RCK( 8) RCK( 9) RCK(10) RCK(11) RCK(12) RCK(13) RCK(14) RCK(15)
        RCK(16) RCK(17) RCK(18) RCK(19) RCK(20) RCK(21) RCK(22) RCK(23)
        RCK(24) RCK(25) RCK(26) RCK(27) RCK(28) RCK(29) RCK(30) RCK(31)
        if (++spin > (1 << 15)) break;   // bail loud (NaN -> absmax), no hang
      } while (inval);
    }

    // ---- h-part: 2-term bf16 over K=1024, 4 chains ----
#pragma unroll
    for (int kc = 0; kc < NKC_H; kc += 4){
      HSTEP2(kc, acc0) HSTEP2(kc + 1, acc1) HSTEP2(kc + 2, acc2) HSTEP2(kc + 3, acc3)
    }
    f32x4 acc = (acc0 + acc1) + (acc2 + acc3);

    // ---- epilogue: gather f/i/c/o via shfl, gates, wave-local stage ----
    float creg[4] = {cr0, cr1, cr2, cr3};
#pragma unroll
    for (int r = 0; r < 4; r++){
      float v = acc[r] + bias;
      float vF = __shfl(v, srcBase);
      float vI = __shfl(v, srcBase + 4);
      float vC = __shfl(v, srcBase + 8);
      float vO = __shfl(v, srcBase + 12);
      if (g == 0){
        float ft = fast_sigmoid(vF);
        float it = fast_sigmoid(vI);
        float gt = fast_tanh(vC);
        float ot = fast_sigmoid(vO);
        float cn = ft * creg[r] + it * gt;
        creg[r] = cn;
        float hn = ot * fast_tanh(cn);
        int si = ((kg << 2) | r) * 4 + (lc & 3);   // row-in-wave * 4 + col
        sh_h[w][si] = f2bf(hn);
        sh_o[w][si] = hn;
      }
    }
    cr0 = creg[0]; cr1 = creg[1]; cr2 = creg[2]; cr3 = creg[3];

    // wave-local LDS visibility (same wave, cross-lane)
    asm volatile("s_waitcnt lgkmcnt(0)" ::: "memory");
    __builtin_amdgcn_sched_barrier(0);

    // ---- per-wave publish: 16 lanes x (8B ring sc0sc1 + 16B out), NO drain ----
    if (lane < 16){
      int row = (w << 4) + lane;
      u32x2  hv2 = *(const u32x2*)&sh_h[w][lane << 2];
      float4 ov  = *(const float4*)&sh_o[w][lane << 2];
      *(float4*)(out + (size_t)t * (BATCH * DL) + row * DL + (bk << 2)) = ov;
      unsigned short* hdst = hRing + (size_t)(t + 1) * (BATCH * DL) + row * DL + (bk << 2);
      asm volatile("global_store_dwordx2 %0, %1, off sc0 sc1"
                   :: "v"(hdst), "v"(hv2) : "memory");
    }

    // ---- prefetch slot t+1 + x-part(t+1) under the load shadow ----
    acc0 = (f32x4){0.f,0.f,0.f,0.f}; acc1 = (f32x4){0.f,0.f,0.f,0.f};
    acc2 = (f32x4){0.f,0.f,0.f,0.f}; acc3 = (f32x4){0.f,0.f,0.f,0.f};
    if (t + 1 < T_STEPS){
      const unsigned short* hbase = hRing + (size_t)(t + 1) * (BATCH * DL) + hOff;
      ISSUE_ALL
      const unsigned short* xRow = xe + (size_t)(t + 1) * BATCH * DI + xOff;
#pragma unroll
      for (int kc = 0; kc < 16; kc += 4){
        XSTEP(kc, acc0) XSTEP(kc + 1, acc1) XSTEP(kc + 2, acc2) XSTEP(kc + 3, acc3)
      }
    }
  }
#undef XSTEP
#undef HSTEP2
#undef LOADHU
#undef ISSUE_ALL
#undef CHK
#undef RLD
#undef RCK
}

extern "C" void kernel_launch(void* const* d_in, const int* in_sizes, int n_in,
                              void* d_out, int out_size, void* d_ws, size_t ws_size,
                              hipStream_t stream){
  const int*   X   = (const int*)d_in[0];
  const float* h0  = (const float*)d_in[1];
  const float* emb = (const float*)d_in[2];
  const float* Wf  = (const float*)d_in[3];
  const float* bf_ = (const float*)d_in[4];
  const float* Wi  = (const float*)d_in[5];
  const float* bi_ = (const float*)d_in[6];
  const float* Wc  = (const float*)d_in[7];
  const float* bc_ = (const float*)d_in[8];
  const float* Wo  = (const float*)d_in[9];
  const float* bo_ = (const float*)d_in[10];
  float* out = (float*)d_out;

  const size_t SLOT = (size_t)BATCH * DL;            // ring slot elems (bf16)
  const size_t ring_elems = SLOT * (size_t)(T_STEPS + 1);

  char* ws = (char*)d_ws;
  size_t off = 0;
  auto alloc = [&](size_t bytes) -> void* {
    void* p = ws + off;
    off = (off + bytes + 255) & ~((size_t)255);
    return p;
  };
  unsigned short* xe        = (unsigned short*)alloc(sizeof(unsigned short) * (size_t)T_STEPS * BATCH * DI);
  unsigned short* W_hi      = (unsigned short*)alloc(sizeof(unsigned short) * (size_t)256 * NKC * 512);
  unsigned short* W_lo      = (unsigned short*)alloc(sizeof(unsigned short) * (size_t)256 * NKC_H * 512);
  unsigned short* hRing     = (unsigned short*)alloc(sizeof(unsigned short) * ring_elems);
  float*          bias_pack = (float*)alloc(sizeof(float) * 4096);
  (void)in_sizes; (void)n_in; (void)out_size; (void)ws_size;

  static bool attr_set = false;
  if (!attr_set){
    hipFuncSetAttribute((const void*)lstm_persist,
                        hipFuncAttributeMaxDynamicSharedMemorySize, 160 * 1024);
    attr_set = true;
  }

  // poison ring (sentinel), then fill slot 0 with h0 (stream-ordered)
  const int n16 = (int)((ring_elems * 2 + 15) / 16);
  hipLaunchKernelGGL(prep_ring, dim3((n16 + 255) / 256), dim3(256), 0, stream,
                     (u32x4*)hRing, n16);
  hipLaunchKernelGGL(prep_xe, dim3(8192), dim3(256), 0, stream, X, emb, xe);
  hipLaunchKernelGGL(prep_w,  dim3(3072), dim3(256), 0, stream, Wf, Wi, Wc, Wo, W_hi, W_lo);
  hipLaunchKernelGGL(prep_h,  dim3(256),  dim3(256), 0, stream, h0, bf_, bi_, bc_, bo_,
                     hRing, bias_pack);
  hipLaunchKernelGGL(lstm_persist, dim3(NBLK), dim3(NTHR), 80 * 1024, stream,
                     xe, W_hi, W_lo, hRing, bias_pack, out);
}

// Round 16
// 5427.515 us; speedup vs baseline: 1.6329x; 1.6329x over previous
//
#include <hip/hip_runtime.h>

// LSTM on MI355X — persistent kernel, round 15.
// Base = R13 (4272us). Changes (one coherent mechanism: take the producer
// DRAIN out of the serial chain, decouple waves):
//  - Producer: ring store (sc0sc1) then IMMEDIATE relaxed fetch_add — no
//    vmcnt(0) drain. Ordering backstop: ring is NaN-poisoned (0xFFFF) each
//    call; consumers validate chunks and retry rare stragglers via sc1
//    bypass loads (immune to the stale-L2 trap).
//  - Detection: 32 counter planes (8 block-groups x 4 waves), each <=32
//    adders + <=32 pollers (proven-safe contention). Waves poll their own
//    plane independently -> ZERO __syncthreads in the main loop.
//  - Loads still issue only AFTER counters confirm arrivals (R14's fatal
//    speculative prefetch removed). Plain-cached chunk loads kept (R9-proven).
// Numerics identical. absmax canary: 0.001953125.

namespace {
constexpr int T_STEPS = 512;
constexpr int BATCH   = 64;
constexpr int DI      = 512;
constexpr int DL      = 1024;
constexpr int NKC     = 48;   // K=1536 in chunks of 32
constexpr int NKC_H   = 32;   // h-part chunks (K=1024)
constexpr int NBLK    = 256;  // grid == CU count
constexpr int NTHR    = 256;  // 4 waves, fully decoupled
constexpr int FPAD    = 32;   // uints per counter slot (128 B)
constexpr unsigned SENT = 0xFFFFFFFFu;   // two bf16 NaNs
}

typedef __attribute__((ext_vector_type(8))) short bf16x8;
typedef __attribute__((ext_vector_type(8))) unsigned short u16x8;
typedef __attribute__((ext_vector_type(4))) float f32x4;
typedef __attribute__((ext_vector_type(4))) unsigned int u32x4;
typedef __attribute__((ext_vector_type(2))) unsigned int u32x2;

__device__ __forceinline__ unsigned short f2bf(float x){
  unsigned int u = __float_as_uint(x);
  return (unsigned short)((u + 0x7FFFu + ((u >> 16) & 1u)) >> 16);
}
__device__ __forceinline__ float bf2f(unsigned short b){
  return __uint_as_float(((unsigned int)b) << 16);
}
__device__ __forceinline__ float fast_sigmoid(float v){
  return __fdividef(1.f, 1.f + __expf(-v));
}
__device__ __forceinline__ float fast_tanh(float v){
  v = fminf(fmaxf(v, -15.f), 15.f);
  float t = __expf(2.f * v);
  return __fdividef(t - 1.f, t + 1.f);
}

// ---------------- prep: poison ring with sentinel ----------------
__global__ void prep_ring(u32x4* __restrict__ dst, int n16){
  int i = blockIdx.x * blockDim.x + threadIdx.x;
  if (i < n16) dst[i] = (u32x4){SENT, SENT, SENT, SENT};
}

// ---------------- prep: embeddings -> bf16 [T*B][DI] ----------------
__global__ void prep_xe(const int* __restrict__ X, const float* __restrict__ emb,
                        unsigned short* __restrict__ xe){
  int i = blockIdx.x * blockDim.x + threadIdx.x;
  const int total = T_STEPS * BATCH * DI / 8;
  if (i >= total) return;
  int row = i >> 6;
  int seg = i & 63;
  int tok = X[row];
  const float* src = emb + (long long)tok * DI + seg * 8;
  float4 v0 = *(const float4*)src;
  float4 v1 = *(const float4*)(src + 4);
  u16x8 o;
  o[0]=f2bf(v0.x); o[1]=f2bf(v0.y); o[2]=f2bf(v0.z); o[3]=f2bf(v0.w);
  o[4]=f2bf(v1.x); o[5]=f2bf(v1.y); o[6]=f2bf(v1.z); o[7]=f2bf(v1.w);
  *(u16x8*)(xe + (long long)row * DI + seg * 8) = o;
}

// ---------------- prep: pack W into MFMA B-fragment layout, hi/lo ----------------
__global__ void prep_w(const float* __restrict__ Wf, const float* __restrict__ Wi,
                       const float* __restrict__ Wc, const float* __restrict__ Wo,
                       unsigned short* __restrict__ W_hi, unsigned short* __restrict__ W_lo){
  int idx = blockIdx.x * blockDim.x + threadIdx.x;
  if (idx >= 256 * NKC * 64) return;
  int lane = idx & 63;
  int kc   = (idx >> 6) % NKC;
  int bk   = idx / (64 * NKC);
  int lc = lane & 15, kg = lane >> 4;
  int g  = lc >> 2;
  int jl = bk * 4 + (lc & 3);
  const float* Wg = (g == 0) ? Wf : ((g == 1) ? Wi : ((g == 2) ? Wc : Wo));
  int kbase = kc * 32 + kg * 8;
  u16x8 hi, lo;
#pragma unroll
  for (int j = 0; j < 8; j++){
    float wv = Wg[(long long)(kbase + j) * DL + jl];
    unsigned short h = f2bf(wv);
    hi[j] = h;
    lo[j] = f2bf(wv - bf2f(h));
  }
  *(u16x8*)(W_hi + ((long long)(bk * NKC + kc) * 64 + lane) * 8) = hi;
  if (kc < NKC_H)
    *(u16x8*)(W_lo + ((long long)(bk * NKC_H + kc) * 64 + lane) * 8) = lo;
}

// ---------------- prep: h0 -> ring slot 0, bias pack, counters zero ----------------
__global__ void prep_h(const float* __restrict__ h0,
                       const float* __restrict__ bf_, const float* __restrict__ bi_,
                       const float* __restrict__ bc_, const float* __restrict__ bo_,
                       unsigned short* __restrict__ hRing,
                       float* __restrict__ bias_pack, unsigned int* __restrict__ bar){
  int i = blockIdx.x * blockDim.x + threadIdx.x;
  if (i < BATCH * DL) hRing[i] = f2bf(h0[i]);      // slot 0 = h_0 (over poison)
  if (i < 4096){
    int r = i & 3, g = (i >> 2) & 3, bk = i >> 4;
    const float* bg = (g == 0) ? bf_ : ((g == 1) ? bi_ : ((g == 2) ? bc_ : bo_));
    bias_pack[i] = bg[bk * 4 + r];
  }
  if (i < 32 * FPAD) bar[i] = 0u;                  // 32 counter planes
}

// ---------------- persistent LSTM: all 512 steps in one kernel ----------------
__launch_bounds__(NTHR, 1)
__global__ void lstm_persist(const unsigned short* __restrict__ xe,
                             const unsigned short* __restrict__ W_hi,
                             const unsigned short* __restrict__ W_lo,
                             unsigned short* __restrict__ hRing,   // [T+1][B*DL]
                             const float* __restrict__ bias_pack,
                             float* __restrict__ out,
                             unsigned int* __restrict__ bar){
  extern __shared__ unsigned short lds[];
  unsigned short* lds_hi = lds;              // NKC  *512 elems (48 KB)
  unsigned short* lds_lo = lds + NKC * 512;  // NKC_H*512 elems (32 KB)
  __shared__ __align__(8)  unsigned short sh_h[4][64];  // per-wave h stage
  __shared__ __align__(16) float          sh_o[4][64];  // per-wave out stage
  const int tid  = threadIdx.x;
  const int bk   = blockIdx.x;
  const int w    = tid >> 6;
  const int lane = tid & 63;

  // stage W once (only __syncthreads in the kernel)
  const uint4* srcHi = (const uint4*)(W_hi + (size_t)bk * NKC * 512);
  uint4* dHi = (uint4*)lds_hi;
  for (int i = tid; i < 3072; i += NTHR) dHi[i] = srcHi[i];
  const uint4* srcLo = (const uint4*)(W_lo + (size_t)bk * NKC_H * 512);
  uint4* dLo = (uint4*)lds_lo;
  for (int i = tid; i < 2048; i += NTHR) dLo[i] = srcLo[i];
  __syncthreads();

  const int lc = lane & 15;
  const int kg = lane >> 4;
  const int g  = lc >> 2;
  const int rowb = (w << 4) + lc;
  const float bias = bias_pack[bk * 16 + lc];
  const int srcBase = (lane & 48) | (lc & 3);
  const int hOff = rowb * DL + kg * 8;     // u16 elements
  const int xOff = rowb * DI + kg * 8;
  // counter planes: [group g = bk>>5][wave w]; adders: 32 blocks' wave-w;
  // pollers: wave-w of all blocks reads lanes' g = lane&7 of its plane.
  unsigned int* myCtr = bar + (((bk >> 5) << 2) | w) * FPAD;
  unsigned int* pollp = bar + (((lane & 7) << 2) | w) * FPAD;
  float cr0 = 0.f, cr1 = 0.f, cr2 = 0.f, cr3 = 0.f;

  f32x4 acc0 = {0.f,0.f,0.f,0.f}, acc1 = {0.f,0.f,0.f,0.f};
  f32x4 acc2 = {0.f,0.f,0.f,0.f}, acc3 = {0.f,0.f,0.f,0.f};
  u32x4 hv[32];

#define XSTEP(KC, ACC) {                                                        \
    bf16x8 ax = *(const bf16x8*)(xRow + (KC) * 32);                             \
    bf16x8 bh = *(const bf16x8*)(lds_hi + (NKC_H + (KC)) * 512 + lane * 8);     \
    ACC = __builtin_amdgcn_mfma_f32_16x16x32_bf16(ax, bh, ACC, 0, 0, 0); }
#define HSTEP2(KC, ACC) {                                                       \
    bf16x8 ah = *(const bf16x8*)&hv[KC];                                        \
    bf16x8 bh = *(const bf16x8*)(lds_hi + (KC) * 512 + lane * 8);               \
    bf16x8 bl = *(const bf16x8*)(lds_lo + (KC) * 512 + lane * 8);               \
    ACC = __builtin_amdgcn_mfma_f32_16x16x32_bf16(ah, bh, ACC, 0, 0, 0);        \
    ACC = __builtin_amdgcn_mfma_f32_16x16x32_bf16(ah, bl, ACC, 0, 0, 0); }
#define LOADHC(I, OFFSTR)                                                       \
    asm volatile("global_load_dwordx4 %0, %1, off offset:" OFFSTR               \
                 : "=v"(hv[I]) : "v"(hbase));
#define LOADHU(I, OFFSTR)                                                       \
    asm volatile("global_load_dwordx4 %0, %1, off offset:" OFFSTR " sc0 sc1"    \
                 : "=v"(hv[I]) : "v"(hbase));
#define CHK(KC) { int bad = (hv[KC][0] == SENT) | (hv[KC][2] == SENT);          \
                  if (__any(bad)) inval |= (1u << (KC)); }
#define RLD(KC, OFFSTR) if (inval & (1u << (KC))) { LOADHU(KC, OFFSTR) }
#define RCK(KC) if (inval & (1u << (KC))) {                                     \
                  int bad = (hv[KC][0] == SENT) | (hv[KC][2] == SENT);          \
                  if (!__any(bad)) inval &= ~(1u << (KC)); }

  // prologue: x-part for step 0
  {
    const unsigned short* xRow = xe + xOff;
#pragma unroll
    for (int kc = 0; kc < 16; kc += 4){
      XSTEP(kc, acc0) XSTEP(kc + 1, acc1) XSTEP(kc + 2, acc2) XSTEP(kc + 3, acc3)
    }
  }

#pragma unroll 1
  for (int t = 0; t < T_STEPS; ++t){
    // ---- per-wave wait: my plane's 8 group counters >= 32*t ----
    if (t > 0){
      const unsigned tgt = 32u * (unsigned)t;
      int spin = 0;
      for (;;){
        unsigned v = __hip_atomic_load(pollp, __ATOMIC_RELAXED, __HIP_MEMORY_SCOPE_AGENT);
        if (__all((v >= tgt) ? 1 : 0)) break;
        __builtin_amdgcn_s_sleep(1);
        if (++spin > (1 << 16)) break;   // bail loud, don't hang
      }
    }

    // ---- issue all 32 h loads (plain cached; arrivals confirmed) ----
    const unsigned short* hbase = hRing + (size_t)t * (BATCH * DL) + hOff;
    LOADHC( 0,"0")    LOADHC( 1,"64")   LOADHC( 2,"128")  LOADHC( 3,"192")
    LOADHC( 4,"256")  LOADHC( 5,"320")  LOADHC( 6,"384")  LOADHC( 7,"448")
    LOADHC( 8,"512")  LOADHC( 9,"576")  LOADHC(10,"640")  LOADHC(11,"704")
    LOADHC(12,"768")  LOADHC(13,"832")  LOADHC(14,"896")  LOADHC(15,"960")
    LOADHC(16,"1024") LOADHC(17,"1088") LOADHC(18,"1152") LOADHC(19,"1216")
    LOADHC(20,"1280") LOADHC(21,"1344") LOADHC(22,"1408") LOADHC(23,"1472")
    LOADHC(24,"1536") LOADHC(25,"1600") LOADHC(26,"1664") LOADHC(27,"1728")
    LOADHC(28,"1792") LOADHC(29,"1856") LOADHC(30,"1920") LOADHC(31,"1984")
    asm volatile("s_waitcnt vmcnt(0)" ::: "memory");
    __builtin_amdgcn_sched_barrier(0);

    // ---- sentinel backstop: retry rare stragglers via sc1 bypass ----
    unsigned inval = 0u;
    CHK( 0) CHK( 1) CHK( 2) CHK( 3) CHK( 4) CHK( 5) CHK( 6) CHK( 7)
    CHK( 8) CHK( 9) CHK(10) CHK(11) CHK(12) CHK(13) CHK(14) CHK(15)
    CHK(16) CHK(17) CHK(18) CHK(19) CHK(20) CHK(21) CHK(22) CHK(23)
    CHK(24) CHK(25) CHK(26) CHK(27) CHK(28) CHK(29) CHK(30) CHK(31)
    if (__builtin_expect(inval != 0u, 0)){
      int spin = 0;
      do {
        RLD( 0,"0")    RLD( 1,"64")   RLD( 2,"128")  RLD( 3,"192")
        RLD( 4,"256")  RLD( 5,"320")  RLD( 6,"384")  RLD( 7,"448")
        RLD( 8,"512")  RLD( 9,"576")  RLD(10,"640")  RLD(11,"704")
        RLD(12,"768")  RLD(13,"832")  RLD(14,"896")  RLD(15,"960")
        RLD(16,"1024") RLD(17,"1088") RLD(18,"1152") RLD(19,"1216")
        RLD(20,"1280") RLD(21,"1344") RLD(22,"1408") RLD(23,"1472")
        RLD(24,"1536") RLD(25,"1600") RLD(26,"1664") RLD(27,"1728")
        RLD(28,"1792") RLD(29,"1856") RLD(30,"1920") RLD(31,"1984")
        asm volatile("s_waitcnt vmcnt(0)" ::: "memory");
        __builtin_amdgcn_sched_barrier(0);
        RCK( 0) RCK( 1) RCK( 2) RCK( 3) RCK( 4) RCK( 5) RCK( 6) RCK( 7)
        RCK( 8) RCK( 9) RCK(10) RCK(11) RCK(12) RCK(13) RCK(14) RCK(15)
        RCK(16) RCK(17) RCK(18) RCK(19) RCK(20) RCK(21) RCK(22) RCK(23)
        RCK(24) RCK(25) RCK(26) RCK(27) RCK(28) RCK(29) RCK(30) RCK(31)
        if (inval) __builtin_amdgcn_s_sleep(1);
        if (++spin > (1 << 15)) break;   // bail loud (NaN -> absmax)
      } while (inval);
    }

    // ---- h-part: 2-term bf16 over K=1024, 4 chains ----
#pragma unroll
    for (int kc = 0; kc < NKC_H; kc += 4){
      HSTEP2(kc, acc0) HSTEP2(kc + 1, acc1) HSTEP2(kc + 2, acc2) HSTEP2(kc + 3, acc3)
    }
    f32x4 acc = (acc0 + acc1) + (acc2 + acc3);

    // ---- epilogue (per wave): shfl gather, gates, wave-local stage ----
    float creg[4] = {cr0, cr1, cr2, cr3};
#pragma unroll
    for (int r = 0; r < 4; r++){
      float v = acc[r] + bias;
      float vF = __shfl(v, srcBase);
      float vI = __shfl(v, srcBase + 4);
      float vC = __shfl(v, srcBase + 8);
      float vO = __shfl(v, srcBase + 12);
      if (g == 0){
        float ft = fast_sigmoid(vF);
        float it = fast_sigmoid(vI);
        float gt = fast_tanh(vC);
        float ot = fast_sigmoid(vO);
        float cn = ft * creg[r] + it * gt;
        creg[r] = cn;
        float hn = ot * fast_tanh(cn);
        int si = (((kg << 2) | r) << 2) | (lc & 3);   // row-in-wave*4 + col
        sh_h[w][si] = f2bf(hn);
        sh_o[w][si] = hn;
      }
    }
    cr0 = creg[0]; cr1 = creg[1]; cr2 = creg[2]; cr3 = creg[3];

    // same-wave LDS visibility
    asm volatile("s_waitcnt lgkmcnt(0)" ::: "memory");
    __builtin_amdgcn_sched_barrier(0);

    // ---- per-wave publish (16 lanes), NO drain, then arrive ----
    if (lane < 16){
      int row = (w << 4) + lane;
      u32x2  hv2 = *(const u32x2*)&sh_h[w][lane << 2];
      float4 ov  = *(const float4*)&sh_o[w][lane << 2];
      *(float4*)(out + (size_t)t * (BATCH * DL) + row * DL + (bk << 2)) = ov;
      unsigned short* hdst = hRing + (size_t)(t + 1) * (BATCH * DL) + row * DL + (bk << 2);
      asm volatile("global_store_dwordx2 %0, %1, off sc0 sc1"
                   :: "v"(hdst), "v"(hv2) : "memory");
    }
    if (lane == 0)
      __hip_atomic_fetch_add(myCtr, 1u, __ATOMIC_RELAXED, __HIP_MEMORY_SCOPE_AGENT);

    // ---- overlap: x-part MFMAs for step t+1 ----
    acc0 = (f32x4){0.f,0.f,0.f,0.f}; acc1 = (f32x4){0.f,0.f,0.f,0.f};
    acc2 = (f32x4){0.f,0.f,0.f,0.f}; acc3 = (f32x4){0.f,0.f,0.f,0.f};
    if (t + 1 < T_STEPS){
      const unsigned short* xRow = xe + (size_t)(t + 1) * BATCH * DI + xOff;
#pragma unroll
      for (int kc = 0; kc < 16; kc += 4){
        XSTEP(kc, acc0) XSTEP(kc + 1, acc1) XSTEP(kc + 2, acc2) XSTEP(kc + 3, acc3)
      }
    }
  }
#undef XSTEP
#undef HSTEP2
#undef LOADHC
#undef LOADHU
#undef CHK
#undef RLD
#undef RCK
}

extern "C" void kernel_launch(void* const* d_in, const int* in_sizes, int n_in,
                              void* d_out, int out_size, void* d_ws, size_t ws_size,
                              hipStream_t stream){
  const int*   X   = (const int*)d_in[0];
  const float* h0  = (const float*)d_in[1];
  const float* emb = (const float*)d_in[2];
  const float* Wf  = (const float*)d_in[3];
  const float* bf_ = (const float*)d_in[4];
  const float* Wi  = (const float*)d_in[5];
  const float* bi_ = (const float*)d_in[6];
  const float* Wc  = (const float*)d_in[7];
  const float* bc_ = (const float*)d_in[8];
  const float* Wo  = (const float*)d_in[9];
  const float* bo_ = (const float*)d_in[10];
  float* out = (float*)d_out;

  const size_t SLOT = (size_t)BATCH * DL;
  const size_t ring_elems = SLOT * (size_t)(T_STEPS + 1);

  char* ws = (char*)d_ws;
  size_t off = 0;
  auto alloc = [&](size_t bytes) -> void* {
    void* p = ws + off;
    off = (off + bytes + 255) & ~((size_t)255);
    return p;
  };
  unsigned short* xe        = (unsigned short*)alloc(sizeof(unsigned short) * (size_t)T_STEPS * BATCH * DI);
  unsigned short* W_hi      = (unsigned short*)alloc(sizeof(unsigned short) * (size_t)256 * NKC * 512);
  unsigned short* W_lo      = (unsigned short*)alloc(sizeof(unsigned short) * (size_t)256 * NKC_H * 512);
  unsigned short* hRing     = (unsigned short*)alloc(sizeof(unsigned short) * ring_elems);
  float*          bias_pack = (float*)alloc(sizeof(float) * 4096);
  unsigned int*   bar       = (unsigned int*)alloc(sizeof(unsigned int) * 32 * FPAD);
  (void)in_sizes; (void)n_in; (void)out_size; (void)ws_size;

  static bool attr_set = false;
  if (!attr_set){
    hipFuncSetAttribute((const void*)lstm_persist,
                        hipFuncAttributeMaxDynamicSharedMemorySize, 160 * 1024);
    attr_set = true;
  }

  // poison ring, then overwrite slot 0 with h_0 (stream-ordered)
  const int n16 = (int)((ring_elems * 2 + 15) / 16);
  hipLaunchKernelGGL(prep_ring, dim3((n16 + 255) / 256), dim3(256), 0, stream,
                     (u32x4*)hRing, n16);
  hipLaunchKernelGGL(prep_xe, dim3(8192), dim3(256), 0, stream, X, emb, xe);
  hipLaunchKernelGGL(prep_w,  dim3(3072), dim3(256), 0, stream, Wf, Wi, Wc, Wo, W_hi, W_lo);
  hipLaunchKernelGGL(prep_h,  dim3(256),  dim3(256), 0, stream, h0, bf_, bi_, bc_, bo_,
                     hRing, bias_pack, bar);
  hipLaunchKernelGGL(lstm_persist, dim3(NBLK), dim3(NTHR), 80 * 1024, stream,
                     xe, W_hi, W_lo, hRing, bias_pack, out, bar);
}

// Round 17
// 4413.159 us; speedup vs baseline: 2.0082x; 1.2298x over previous
//
#include <hip/hip_runtime.h>

// LSTM on MI355X — persistent kernel, round 16.
// Base = R13 (best 4272us). ONE mechanism change: SPLIT-HALF PHASED ARRIVAL.
// Counters regrouped by bk>>5 (groups 0-3 = blocks 0-127 = h cols 0-511;
// groups 4-7 = cols 512-1023). Consumer: pollA -> sync -> issue A-loads ->
// pollB (overlaps A-load flight) -> sync -> issue B-loads -> vmcnt -> compute.
// Lockstep case degenerates to exactly R13 (no loss); jitter case trims the
// B-half detect off the critical path. Poll sleep 2->1. Everything else
// byte-identical to R13. absmax canary: 0.001953125.

namespace {
constexpr int T_STEPS = 512;
constexpr int BATCH   = 64;
constexpr int DI      = 512;
constexpr int DL      = 1024;
constexpr int NKC     = 48;   // K=1536 in chunks of 32
constexpr int NKC_H   = 32;   // h-part chunks (K=1024)
constexpr int NBLK    = 256;  // grid == CU count, 1 block/CU resident
constexpr int NTHR    = 256;  // 4 compute waves
constexpr int FPAD    = 32;   // uints per counter slot (128 B padding)
}

typedef __attribute__((ext_vector_type(8))) short bf16x8;
typedef __attribute__((ext_vector_type(8))) unsigned short u16x8;
typedef __attribute__((ext_vector_type(4))) float f32x4;
typedef __attribute__((ext_vector_type(4))) unsigned int u32x4;
typedef __attribute__((ext_vector_type(2))) unsigned int u32x2;

__device__ __forceinline__ unsigned short f2bf(float x){
  unsigned int u = __float_as_uint(x);
  return (unsigned short)((u + 0x7FFFu + ((u >> 16) & 1u)) >> 16);
}
__device__ __forceinline__ float bf2f(unsigned short b){
  return __uint_as_float(((unsigned int)b) << 16);
}
__device__ __forceinline__ float fast_sigmoid(float v){
  return __fdividef(1.f, 1.f + __expf(-v));
}
__device__ __forceinline__ float fast_tanh(float v){
  v = fminf(fmaxf(v, -15.f), 15.f);
  float t = __expf(2.f * v);
  return __fdividef(t - 1.f, t + 1.f);
}

// ---------------- prep: embeddings -> bf16 [T*B][DI] ----------------
__global__ void prep_xe(const int* __restrict__ X, const float* __restrict__ emb,
                        unsigned short* __restrict__ xe){
  int i = blockIdx.x * blockDim.x + threadIdx.x;
  const int total = T_STEPS * BATCH * DI / 8;
  if (i >= total) return;
  int row = i >> 6;
  int seg = i & 63;
  int tok = X[row];
  const float* src = emb + (long long)tok * DI + seg * 8;
  float4 v0 = *(const float4*)src;
  float4 v1 = *(const float4*)(src + 4);
  u16x8 o;
  o[0]=f2bf(v0.x); o[1]=f2bf(v0.y); o[2]=f2bf(v0.z); o[3]=f2bf(v0.w);
  o[4]=f2bf(v1.x); o[5]=f2bf(v1.y); o[6]=f2bf(v1.z); o[7]=f2bf(v1.w);
  *(u16x8*)(xe + (long long)row * DI + seg * 8) = o;
}

// ---------------- prep: pack W into MFMA B-fragment layout, hi/lo ----------------
__global__ void prep_w(const float* __restrict__ Wf, const float* __restrict__ Wi,
                       const float* __restrict__ Wc, const float* __restrict__ Wo,
                       unsigned short* __restrict__ W_hi, unsigned short* __restrict__ W_lo){
  int idx = blockIdx.x * blockDim.x + threadIdx.x;
  if (idx >= 256 * NKC * 64) return;
  int lane = idx & 63;
  int kc   = (idx >> 6) % NKC;
  int bk   = idx / (64 * NKC);
  int lc = lane & 15, kg = lane >> 4;
  int g  = lc >> 2;
  int jl = bk * 4 + (lc & 3);
  const float* Wg = (g == 0) ? Wf : ((g == 1) ? Wi : ((g == 2) ? Wc : Wo));
  int kbase = kc * 32 + kg * 8;
  u16x8 hi, lo;
#pragma unroll
  for (int j = 0; j < 8; j++){
    float wv = Wg[(long long)(kbase + j) * DL + jl];
    unsigned short h = f2bf(wv);
    hi[j] = h;
    lo[j] = f2bf(wv - bf2f(h));
  }
  *(u16x8*)(W_hi + ((long long)(bk * NKC + kc) * 64 + lane) * 8) = hi;
  if (kc < NKC_H)
    *(u16x8*)(W_lo + ((long long)(bk * NKC_H + kc) * 64 + lane) * 8) = lo;
}

// ---------------- prep: h0 -> ring slot 0 (bf16), bias pack, counters zero ----------------
__global__ void prep_h(const float* __restrict__ h0,
                       const float* __restrict__ bf_, const float* __restrict__ bi_,
                       const float* __restrict__ bc_, const float* __restrict__ bo_,
                       unsigned short* __restrict__ hRing,
                       float* __restrict__ bias_pack, unsigned int* __restrict__ bar){
  int i = blockIdx.x * blockDim.x + threadIdx.x;
  if (i < BATCH * DL) hRing[i] = f2bf(h0[i]);      // slot 0 = h_0
  if (i < 4096){
    int r = i & 3, g = (i >> 2) & 3, bk = i >> 4;
    const float* bg = (g == 0) ? bf_ : ((g == 1) ? bi_ : ((g == 2) ? bc_ : bo_));
    bias_pack[i] = bg[bk * 4 + r];
  }
  if (i < 8 * FPAD) bar[i] = 0u;                   // 8 counter lines
}

// ---------------- persistent LSTM: all 512 steps in one kernel ----------------
// CACHED=true : ring depth T+1 (write-once), consumer loads plain cached.
// CACHED=false: ring depth 2 (double buffer),  consumer loads sc0 sc1.
template<bool CACHED>
__launch_bounds__(NTHR, 1)
__global__ void lstm_persist(const unsigned short* __restrict__ xe,
                             const unsigned short* __restrict__ W_hi,
                             const unsigned short* __restrict__ W_lo,
                             unsigned short* __restrict__ hRing,
                             const float* __restrict__ bias_pack,
                             float* __restrict__ out,
                             unsigned int* __restrict__ bar){
  extern __shared__ unsigned short lds[];
  unsigned short* lds_hi = lds;              // NKC  *512 elems (48 KB)
  unsigned short* lds_lo = lds + NKC * 512;  // NKC_H*512 elems (32 KB)
  __shared__ unsigned short stage_h[BATCH * 4];  // bf16 h slice [64 rows][4 cols]
  __shared__ float          stage_o[BATCH * 4];  // out slice
  const int tid  = threadIdx.x;
  const int bk   = blockIdx.x;
  const int w    = tid >> 6;
  const int lane = tid & 63;

  // stage W once for the whole run
  const uint4* srcHi = (const uint4*)(W_hi + (size_t)bk * NKC * 512);
  uint4* dHi = (uint4*)lds_hi;
  for (int i = tid; i < 3072; i += NTHR) dHi[i] = srcHi[i];
  const uint4* srcLo = (const uint4*)(W_lo + (size_t)bk * NKC_H * 512);
  uint4* dLo = (uint4*)lds_lo;
  for (int i = tid; i < 2048; i += NTHR) dLo[i] = srcLo[i];
  __syncthreads();

  const int lc = lane & 15;
  const int kg = lane >> 4;
  const int g  = lc >> 2;
  const int rowb = (w << 4) + lc;
  const float bias = bias_pack[bk * 16 + lc];
  const int srcBase = (lane & 48) | (lc & 3);
  const int hOff = rowb * DL + kg * 8;     // u16 elements
  const int xOff = rowb * DI + kg * 8;
  // counters grouped by bk>>5: groups 0-3 = blocks 0-127 (h cols 0-511,
  // chunks 0-15); groups 4-7 = blocks 128-255 (cols 512-1023, chunks 16-31).
  unsigned int* myCtr  = bar + (bk >> 5) * FPAD;
  unsigned int* pollA  = bar + (lane & 3) * FPAD;        // groups 0..3
  unsigned int* pollB  = bar + (4 + (lane & 3)) * FPAD;  // groups 4..7
  float cr0 = 0.f, cr1 = 0.f, cr2 = 0.f, cr3 = 0.f;

  f32x4 acc0 = {0.f,0.f,0.f,0.f}, acc1 = {0.f,0.f,0.f,0.f};
  f32x4 acc2 = {0.f,0.f,0.f,0.f}, acc3 = {0.f,0.f,0.f,0.f};

#define XSTEP(KC, ACC) {                                                        \
    bf16x8 ax = *(const bf16x8*)(xRow + (KC) * 32);                             \
    bf16x8 bh = *(const bf16x8*)(lds_hi + (NKC_H + (KC)) * 512 + lane * 8);     \
    ACC = __builtin_amdgcn_mfma_f32_16x16x32_bf16(ax, bh, ACC, 0, 0, 0); }
#define HSTEP2(KC, ACC) {                                                       \
    bf16x8 ah = *(const bf16x8*)&hv[KC];                                        \
    bf16x8 bh = *(const bf16x8*)(lds_hi + (KC) * 512 + lane * 8);               \
    bf16x8 bl = *(const bf16x8*)(lds_lo + (KC) * 512 + lane * 8);               \
    ACC = __builtin_amdgcn_mfma_f32_16x16x32_bf16(ah, bh, ACC, 0, 0, 0);        \
    ACC = __builtin_amdgcn_mfma_f32_16x16x32_bf16(ah, bl, ACC, 0, 0, 0); }
#define LOADHC(I, OFFSTR)                                                       \
    asm volatile("global_load_dwordx4 %0, %1, off offset:" OFFSTR               \
                 : "=v"(hv[I]) : "v"(hbase));
#define LOADHU(I, OFFSTR)                                                       \
    asm volatile("global_load_dwordx4 %0, %1, off offset:" OFFSTR " sc0 sc1"    \
                 : "=v"(hv[I]) : "v"(hbase));
#define LOAD_A(M)                                                               \
    M( 0,"0")    M( 1,"64")   M( 2,"128")  M( 3,"192")                          \
    M( 4,"256")  M( 5,"320")  M( 6,"384")  M( 7,"448")                          \
    M( 8,"512")  M( 9,"576")  M(10,"640")  M(11,"704")                          \
    M(12,"768")  M(13,"832")  M(14,"896")  M(15,"960")
#define LOAD_B(M)                                                               \
    M(16,"1024") M(17,"1088") M(18,"1152") M(19,"1216")                         \
    M(20,"1280") M(21,"1344") M(22,"1408") M(23,"1472")                         \
    M(24,"1536") M(25,"1600") M(26,"1664") M(27,"1728")                         \
    M(28,"1792") M(29,"1856") M(30,"1920") M(31,"1984")

  // x-part for step 0
  {
    const unsigned short* xRow = xe + xOff;
#pragma unroll
    for (int kc = 0; kc < 16; kc += 4){
      XSTEP(kc, acc0) XSTEP(kc + 1, acc1) XSTEP(kc + 2, acc2) XSTEP(kc + 3, acc3)
    }
  }

#pragma unroll 1
  for (int t = 0; t < T_STEPS; ++t){
    // ---- phase A wait: groups 0-3 (h cols 0-511) published ----
    if (t > 0 && w == 0){
      const unsigned tgt = 32u * (unsigned)t;
      int spin = 0;
      for (;;){
        unsigned v = __hip_atomic_load(pollA, __ATOMIC_RELAXED, __HIP_MEMORY_SCOPE_AGENT);
        if (__all((v >= tgt) ? 1 : 0)) break;
        __builtin_amdgcn_s_sleep(1);
        if (++spin > (1 << 17)) break;   // bail loud (absmax), don't hang
      }
    }
    __syncthreads();   // A arrivals observed

    const int slotR = CACHED ? t       : (t & 1);
    const int slotW = CACHED ? (t + 1) : ((t + 1) & 1);
    unsigned short* hWr = hRing + (size_t)slotW * (BATCH * DL);
    float* out_t = out + (size_t)t * (BATCH * DL);

    // ---- issue A-half loads (chunks 0-15); they fly during pollB ----
    u32x4 hv[32];
    const unsigned short* hbase = hRing + (size_t)slotR * (BATCH * DL) + hOff;
    if constexpr (CACHED){ LOAD_A(LOADHC) } else { LOAD_A(LOADHU) }

    // ---- phase B wait: groups 4-7 (h cols 512-1023) published ----
    if (t > 0 && w == 0){
      const unsigned tgt = 32u * (unsigned)t;
      int spin = 0;
      for (;;){
        unsigned v = __hip_atomic_load(pollB, __ATOMIC_RELAXED, __HIP_MEMORY_SCOPE_AGENT);
        if (__all((v >= tgt) ? 1 : 0)) break;
        __builtin_amdgcn_s_sleep(1);
        if (++spin > (1 << 17)) break;   // bail loud (absmax), don't hang
      }
    }
    __syncthreads();   // B arrivals observed

    // ---- issue B-half loads (chunks 16-31), wait all, compute ----
    if constexpr (CACHED){ LOAD_B(LOADHC) } else { LOAD_B(LOADHU) }
    asm volatile("s_waitcnt vmcnt(0)" ::: "memory");
    __builtin_amdgcn_sched_barrier(0);

    // ---- h-part: 2-term bf16 over K=1024, 4 chains ----
#pragma unroll
    for (int kc = 0; kc < NKC_H; kc += 4){
      HSTEP2(kc, acc0) HSTEP2(kc + 1, acc1) HSTEP2(kc + 2, acc2) HSTEP2(kc + 3, acc3)
    }
    f32x4 acc = (acc0 + acc1) + (acc2 + acc3);

    // ---- epilogue: gather f/i/c/o via shfl, gates, stage h/out into LDS ----
    float creg[4] = {cr0, cr1, cr2, cr3};
#pragma unroll
    for (int r = 0; r < 4; r++){
      float v = acc[r] + bias;
      float vF = __shfl(v, srcBase);
      float vI = __shfl(v, srcBase + 4);
      float vC = __shfl(v, srcBase + 8);
      float vO = __shfl(v, srcBase + 12);
      if (g == 0){
        int b = (w << 4) | (kg << 2) | r;
        float ft = fast_sigmoid(vF);
        float it = fast_sigmoid(vI);
        float gt = fast_tanh(vC);
        float ot = fast_sigmoid(vO);
        float cn = ft * creg[r] + it * gt;
        creg[r] = cn;
        float hn = ot * fast_tanh(cn);
        int si = (b << 2) | (lc & 3);
        stage_h[si] = f2bf(hn);
        stage_o[si] = hn;
      }
    }
    cr0 = creg[0]; cr1 = creg[1]; cr2 = creg[2]; cr3 = creg[3];

    __syncthreads();   // staging visible to wave 0

    // ---- wave 0: coalesced publish (ring sc0sc1 + out plain), drain, add ----
    if (w == 0){
      u32x2  hv2 = *(const u32x2*)&stage_h[lane << 2];   // 8B = one row's 4 cols
      f32x4  ov  = *(const f32x4*)&stage_o[lane << 2];
      *(float4*)(out_t + lane * DL + (bk << 2)) = *(const float4*)&ov;
      unsigned short* hdst = hWr + lane * DL + (bk << 2);
      asm volatile("global_store_dwordx2 %0, %1, off sc0 sc1"
                   :: "v"(hdst), "v"(hv2) : "memory");
      asm volatile("s_waitcnt vmcnt(0)" ::: "memory");
      __builtin_amdgcn_sched_barrier(0);
      if (tid == 0)
        __hip_atomic_fetch_add(myCtr, 1u, __ATOMIC_RELAXED, __HIP_MEMORY_SCOPE_AGENT);
    }

    // ---- overlap: x-part MFMAs for step t+1 (xe independent of h) ----
    acc0 = (f32x4){0.f,0.f,0.f,0.f}; acc1 = (f32x4){0.f,0.f,0.f,0.f};
    acc2 = (f32x4){0.f,0.f,0.f,0.f}; acc3 = (f32x4){0.f,0.f,0.f,0.f};
    if (t + 1 < T_STEPS){
      const unsigned short* xRow = xe + (size_t)(t + 1) * BATCH * DI + xOff;
#pragma unroll
      for (int kc = 0; kc < 16; kc += 4){
        XSTEP(kc, acc0) XSTEP(kc + 1, acc1) XSTEP(kc + 2, acc2) XSTEP(kc + 3, acc3)
      }
    }
  }
#undef XSTEP
#undef HSTEP2
#undef LOADHC
#undef LOADHU
#undef LOAD_A
#undef LOAD_B
}

extern "C" void kernel_launch(void* const* d_in, const int* in_sizes, int n_in,
                              void* d_out, int out_size, void* d_ws, size_t ws_size,
                              hipStream_t stream){
  const int*   X   = (const int*)d_in[0];
  const float* h0  = (const float*)d_in[1];
  const float* emb = (const float*)d_in[2];
  const float* Wf  = (const float*)d_in[3];
  const float* bf_ = (const float*)d_in[4];
  const float* Wi  = (const float*)d_in[5];
  const float* bi_ = (const float*)d_in[6];
  const float* Wc  = (const float*)d_in[7];
  const float* bc_ = (const float*)d_in[8];
  const float* Wo  = (const float*)d_in[9];
  const float* bo_ = (const float*)d_in[10];
  float* out = (float*)d_out;

  const size_t SLOT = (size_t)BATCH * DL;            // ring slot elems (bf16)
  const size_t base_need =
      sizeof(unsigned short) * ((size_t)T_STEPS * BATCH * DI        // xe
                              + (size_t)256 * NKC * 512             // W_hi
                              + (size_t)256 * NKC_H * 512)          // W_lo
    + sizeof(float) * 4096                                           // bias
    + sizeof(unsigned int) * 8 * FPAD + 4096;                        // bar + slack
  const size_t ring_full = sizeof(unsigned short) * SLOT * (size_t)(T_STEPS + 1);
  const bool cached = ws_size >= base_need + ring_full;
  const size_t ring_elems = cached ? SLOT * (size_t)(T_STEPS + 1) : SLOT * 2;

  char* ws = (char*)d_ws;
  size_t off = 0;
  auto alloc = [&](size_t bytes) -> void* {
    void* p = ws + off;
    off = (off + bytes + 255) & ~((size_t)255);
    return p;
  };
  unsigned short* xe        = (unsigned short*)alloc(sizeof(unsigned short) * (size_t)T_STEPS * BATCH * DI);
  unsigned short* W_hi      = (unsigned short*)alloc(sizeof(unsigned short) * (size_t)256 * NKC * 512);
  unsigned short* W_lo      = (unsigned short*)alloc(sizeof(unsigned short) * (size_t)256 * NKC_H * 512);
  unsigned short* hRing     = (unsigned short*)alloc(sizeof(unsigned short) * ring_elems);
  float*          bias_pack = (float*)alloc(sizeof(float) * 4096);
  unsigned int*   bar       = (unsigned int*)alloc(sizeof(unsigned int) * 8 * FPAD);
  (void)in_sizes; (void)n_in; (void)out_size;

  static bool attr_set = false;
  if (!attr_set){
    hipFuncSetAttribute((const void*)lstm_persist<true>,
                        hipFuncAttributeMaxDynamicSharedMemorySize, 160 * 1024);
    hipFuncSetAttribute((const void*)lstm_persist<false>,
                        hipFuncAttributeMaxDynamicSharedMemorySize, 160 * 1024);
    attr_set = true;
  }

  hipLaunchKernelGGL(prep_xe, dim3(8192), dim3(256), 0, stream, X, emb, xe);
  hipLaunchKernelGGL(prep_w,  dim3(3072), dim3(256), 0, stream, Wf, Wi, Wc, Wo, W_hi, W_lo);
  hipLaunchKernelGGL(prep_h,  dim3(256),  dim3(256), 0, stream, h0, bf_, bi_, bc_, bo_,
                     hRing, bias_pack, bar);
  if (cached)
    hipLaunchKernelGGL((lstm_persist<true>),  dim3(NBLK), dim3(NTHR), 80 * 1024, stream,
                       xe, W_hi, W_lo, hRing, bias_pack, out, bar);
  else
    hipLaunchKernelGGL((lstm_persist<false>), dim3(NBLK), dim3(NTHR), 80 * 1024, stream,
                       xe, W_hi, W_lo, hRing, bias_pack, out, bar);
}

// Round 18
// 4264.730 us; speedup vs baseline: 2.0781x; 1.0348x over previous
//
#include <hip/hip_runtime.h>

// LSTM on MI355X — persistent kernel, FINAL (= round 13 champion, 4272us).
// Structure: one persistent kernel runs all 512 timesteps.
//  - W packed once into MFMA B-fragment layout (hi/lo bf16 planes), staged to
//    LDS once (80KB/block, 256 blocks = whole-chip LDS holds W exactly once).
//  - h feedback via write-once bf16 ring hRing[T+1][B*DL]: producers publish
//    with sc0sc1 (write-through to MALL, cross-XCD visible) + vmcnt drain;
//    consumers pre-issue all 32 16B loads plain-cached (L2-shared per XCD;
//    write-once slot => fresh-by-construction, no invalidates anywhere).
//  - Detection: 8 spread relaxed agent fetch_add counters (bk&7; <=32
//    RMWs/line), w0 polls all 8 lines in one memory round (lane&7).
//  - Split-bf16 numerics: h(bf16) x (W_hi + W_lo) 2-term MFMA, fp32 gates.
// absmax canary: 0.001953125 (bf16 quantization floor, 5.7x under threshold).
// Sync-topology variants R11/R12/R14/R15/R16 all within -1.3%/+107% of this;
// remaining 8.3us/step = 512 irreducible cross-die sync rounds (~4 MALL RTs
// + jitter) + ~1.5-2us compute. This is the practical floor for this shape.

namespace {
constexpr int T_STEPS = 512;
constexpr int BATCH   = 64;
constexpr int DI      = 512;
constexpr int DL      = 1024;
constexpr int NKC     = 48;   // K=1536 in chunks of 32
constexpr int NKC_H   = 32;   // h-part chunks (K=1024)
constexpr int NBLK    = 256;  // grid == CU count, 1 block/CU resident
constexpr int NTHR    = 256;  // 4 compute waves
constexpr int FPAD    = 32;   // uints per counter slot (128 B padding)
}

typedef __attribute__((ext_vector_type(8))) short bf16x8;
typedef __attribute__((ext_vector_type(8))) unsigned short u16x8;
typedef __attribute__((ext_vector_type(4))) float f32x4;
typedef __attribute__((ext_vector_type(4))) unsigned int u32x4;
typedef __attribute__((ext_vector_type(2))) unsigned int u32x2;

__device__ __forceinline__ unsigned short f2bf(float x){
  unsigned int u = __float_as_uint(x);
  return (unsigned short)((u + 0x7FFFu + ((u >> 16) & 1u)) >> 16);
}
__device__ __forceinline__ float bf2f(unsigned short b){
  return __uint_as_float(((unsigned int)b) << 16);
}
__device__ __forceinline__ float fast_sigmoid(float v){
  return __fdividef(1.f, 1.f + __expf(-v));
}
__device__ __forceinline__ float fast_tanh(float v){
  v = fminf(fmaxf(v, -15.f), 15.f);
  float t = __expf(2.f * v);
  return __fdividef(t - 1.f, t + 1.f);
}

// ---------------- prep: embeddings -> bf16 [T*B][DI] ----------------
__global__ void prep_xe(const int* __restrict__ X, const float* __restrict__ emb,
                        unsigned short* __restrict__ xe){
  int i = blockIdx.x * blockDim.x + threadIdx.x;
  const int total = T_STEPS * BATCH * DI / 8;
  if (i >= total) return;
  int row = i >> 6;
  int seg = i & 63;
  int tok = X[row];
  const float* src = emb + (long long)tok * DI + seg * 8;
  float4 v0 = *(const float4*)src;
  float4 v1 = *(const float4*)(src + 4);
  u16x8 o;
  o[0]=f2bf(v0.x); o[1]=f2bf(v0.y); o[2]=f2bf(v0.z); o[3]=f2bf(v0.w);
  o[4]=f2bf(v1.x); o[5]=f2bf(v1.y); o[6]=f2bf(v1.z); o[7]=f2bf(v1.w);
  *(u16x8*)(xe + (long long)row * DI + seg * 8) = o;
}

// ---------------- prep: pack W into MFMA B-fragment layout, hi/lo ----------------
__global__ void prep_w(const float* __restrict__ Wf, const float* __restrict__ Wi,
                       const float* __restrict__ Wc, const float* __restrict__ Wo,
                       unsigned short* __restrict__ W_hi, unsigned short* __restrict__ W_lo){
  int idx = blockIdx.x * blockDim.x + threadIdx.x;
  if (idx >= 256 * NKC * 64) return;
  int lane = idx & 63;
  int kc   = (idx >> 6) % NKC;
  int bk   = idx / (64 * NKC);
  int lc = lane & 15, kg = lane >> 4;
  int g  = lc >> 2;
  int jl = bk * 4 + (lc & 3);
  const float* Wg = (g == 0) ? Wf : ((g == 1) ? Wi : ((g == 2) ? Wc : Wo));
  int kbase = kc * 32 + kg * 8;
  u16x8 hi, lo;
#pragma unroll
  for (int j = 0; j < 8; j++){
    float wv = Wg[(long long)(kbase + j) * DL + jl];
    unsigned short h = f2bf(wv);
    hi[j] = h;
    lo[j] = f2bf(wv - bf2f(h));
  }
  *(u16x8*)(W_hi + ((long long)(bk * NKC + kc) * 64 + lane) * 8) = hi;
  if (kc < NKC_H)
    *(u16x8*)(W_lo + ((long long)(bk * NKC_H + kc) * 64 + lane) * 8) = lo;
}

// ---------------- prep: h0 -> ring slot 0 (bf16), bias pack, counters zero ----------------
__global__ void prep_h(const float* __restrict__ h0,
                       const float* __restrict__ bf_, const float* __restrict__ bi_,
                       const float* __restrict__ bc_, const float* __restrict__ bo_,
                       unsigned short* __restrict__ hRing,
                       float* __restrict__ bias_pack, unsigned int* __restrict__ bar){
  int i = blockIdx.x * blockDim.x + threadIdx.x;
  if (i < BATCH * DL) hRing[i] = f2bf(h0[i]);      // slot 0 = h_0
  if (i < 4096){
    int r = i & 3, g = (i >> 2) & 3, bk = i >> 4;
    const float* bg = (g == 0) ? bf_ : ((g == 1) ? bi_ : ((g == 2) ? bc_ : bo_));
    bias_pack[i] = bg[bk * 4 + r];
  }
  if (i < 8 * FPAD) bar[i] = 0u;                   // 8 counter lines
}

// ---------------- persistent LSTM: all 512 steps in one kernel ----------------
// CACHED=true : ring depth T+1 (write-once), consumer loads plain cached.
// CACHED=false: ring depth 2 (double buffer),  consumer loads sc0 sc1 (=R6).
template<bool CACHED>
__launch_bounds__(NTHR, 1)
__global__ void lstm_persist(const unsigned short* __restrict__ xe,
                             const unsigned short* __restrict__ W_hi,
                             const unsigned short* __restrict__ W_lo,
                             unsigned short* __restrict__ hRing,
                             const float* __restrict__ bias_pack,
                             float* __restrict__ out,
                             unsigned int* __restrict__ bar){
  extern __shared__ unsigned short lds[];
  unsigned short* lds_hi = lds;              // NKC  *512 elems (48 KB)
  unsigned short* lds_lo = lds + NKC * 512;  // NKC_H*512 elems (32 KB)
  __shared__ unsigned short stage_h[BATCH * 4];  // bf16 h slice [64 rows][4 cols]
  __shared__ float          stage_o[BATCH * 4];  // out slice
  const int tid  = threadIdx.x;
  const int bk   = blockIdx.x;
  const int w    = tid >> 6;
  const int lane = tid & 63;

  // stage W once for the whole run
  const uint4* srcHi = (const uint4*)(W_hi + (size_t)bk * NKC * 512);
  uint4* dHi = (uint4*)lds_hi;
  for (int i = tid; i < 3072; i += NTHR) dHi[i] = srcHi[i];
  const uint4* srcLo = (const uint4*)(W_lo + (size_t)bk * NKC_H * 512);
  uint4* dLo = (uint4*)lds_lo;
  for (int i = tid; i < 2048; i += NTHR) dLo[i] = srcLo[i];
  __syncthreads();

  const int lc = lane & 15;
  const int kg = lane >> 4;
  const int g  = lc >> 2;
  const int rowb = (w << 4) + lc;
  const float bias = bias_pack[bk * 16 + lc];
  const int srcBase = (lane & 48) | (lc & 3);
  const int hOff = rowb * DL + kg * 8;     // u16 elements
  const int xOff = rowb * DI + kg * 8;
  unsigned int* myCtr = bar + (bk & 7) * FPAD;
  unsigned int* pollp = bar + (lane & 7) * FPAD;   // 64 lanes cover 8 lines
  float cr0 = 0.f, cr1 = 0.f, cr2 = 0.f, cr3 = 0.f;

  f32x4 acc0 = {0.f,0.f,0.f,0.f}, acc1 = {0.f,0.f,0.f,0.f};
  f32x4 acc2 = {0.f,0.f,0.f,0.f}, acc3 = {0.f,0.f,0.f,0.f};

#define XSTEP(KC, ACC) {                                                        \
    bf16x8 ax = *(const bf16x8*)(xRow + (KC) * 32);                             \
    bf16x8 bh = *(const bf16x8*)(lds_hi + (NKC_H + (KC)) * 512 + lane * 8);     \
    ACC = __builtin_amdgcn_mfma_f32_16x16x32_bf16(ax, bh, ACC, 0, 0, 0); }
#define HSTEP2(KC, ACC) {                                                       \
    bf16x8 ah = *(const bf16x8*)&hv[KC];                                        \
    bf16x8 bh = *(const bf16x8*)(lds_hi + (KC) * 512 + lane * 8);               \
    bf16x8 bl = *(const bf16x8*)(lds_lo + (KC) * 512 + lane * 8);               \
    ACC = __builtin_amdgcn_mfma_f32_16x16x32_bf16(ah, bh, ACC, 0, 0, 0);        \
    ACC = __builtin_amdgcn_mfma_f32_16x16x32_bf16(ah, bl, ACC, 0, 0, 0); }
#define LOADHC(I, OFFSTR)                                                       \
    asm volatile("global_load_dwordx4 %0, %1, off offset:" OFFSTR               \
                 : "=v"(hv[I]) : "v"(hbase));
#define LOADHU(I, OFFSTR)                                                       \
    asm volatile("global_load_dwordx4 %0, %1, off offset:" OFFSTR " sc0 sc1"    \
                 : "=v"(hv[I]) : "v"(hbase));

  // x-part for step 0
  {
    const unsigned short* xRow = xe + xOff;
#pragma unroll
    for (int kc = 0; kc < 16; kc += 4){
      XSTEP(kc, acc0) XSTEP(kc + 1, acc1) XSTEP(kc + 2, acc2) XSTEP(kc + 3, acc3)
    }
  }

#pragma unroll 1
  for (int t = 0; t < T_STEPS; ++t){
    // ---- wait: all 8 counters >= 32*t (w0 polls; 1 memory round/poll) ----
    if (t > 0 && w == 0){
      const unsigned tgt = 32u * (unsigned)t;
      int spin = 0;
      for (;;){
        unsigned v = __hip_atomic_load(pollp, __ATOMIC_RELAXED, __HIP_MEMORY_SCOPE_AGENT);
        if (__all((v >= tgt) ? 1 : 0)) break;
        __builtin_amdgcn_s_sleep(2);
        if (++spin > (1 << 16)) break;   // bail loud (absmax), don't hang
      }
      // no fence needed: CACHED -> write-once ring (fresh-by-construction);
      // !CACHED -> sc1 loads bypass L1/L2
    }
    __syncthreads();   // A: arrivals observed -> all waves may read h_t

    const int slotR = CACHED ? t       : (t & 1);
    const int slotW = CACHED ? (t + 1) : ((t + 1) & 1);
    unsigned short* hWr = hRing + (size_t)slotW * (BATCH * DL);
    float* out_t = out + (size_t)t * (BATCH * DL);

    // ---- pre-issue all 32 h loads (16B each, stride 64B) ----
    u32x4 hv[32];
    const unsigned short* hbase = hRing + (size_t)slotR * (BATCH * DL) + hOff;
    if constexpr (CACHED){
      LOADHC( 0,"0")    LOADHC( 1,"64")   LOADHC( 2,"128")  LOADHC( 3,"192")
      LOADHC( 4,"256")  LOADHC( 5,"320")  LOADHC( 6,"384")  LOADHC( 7,"448")
      LOADHC( 8,"512")  LOADHC( 9,"576")  LOADHC(10,"640")  LOADHC(11,"704")
      LOADHC(12,"768")  LOADHC(13,"832")  LOADHC(14,"896")  LOADHC(15,"960")
      LOADHC(16,"1024") LOADHC(17,"1088") LOADHC(18,"1152") LOADHC(19,"1216")
      LOADHC(20,"1280") LOADHC(21,"1344") LOADHC(22,"1408") LOADHC(23,"1472")
      LOADHC(24,"1536") LOADHC(25,"1600") LOADHC(26,"1664") LOADHC(27,"1728")
      LOADHC(28,"1792") LOADHC(29,"1856") LOADHC(30,"1920") LOADHC(31,"1984")
    } else {
      LOADHU( 0,"0")    LOADHU( 1,"64")   LOADHU( 2,"128")  LOADHU( 3,"192")
      LOADHU( 4,"256")  LOADHU( 5,"320")  LOADHU( 6,"384")  LOADHU( 7,"448")
      LOADHU( 8,"512")  LOADHU( 9,"576")  LOADHU(10,"640")  LOADHU(11,"704")
      LOADHU(12,"768")  LOADHU(13,"832")  LOADHU(14,"896")  LOADHU(15,"960")
      LOADHU(16,"1024") LOADHU(17,"1088") LOADHU(18,"1152") LOADHU(19,"1216")
      LOADHU(20,"1280") LOADHU(21,"1344") LOADHU(22,"1408") LOADHU(23,"1472")
      LOADHU(24,"1536") LOADHU(25,"1600") LOADHU(26,"1664") LOADHU(27,"1728")
      LOADHU(28,"1792") LOADHU(29,"1856") LOADHU(30,"1920") LOADHU(31,"1984")
    }
    asm volatile("s_waitcnt vmcnt(0)" ::: "memory");
    __builtin_amdgcn_sched_barrier(0);

    // ---- h-part: 2-term bf16 over K=1024, 4 chains ----
#pragma unroll
    for (int kc = 0; kc < NKC_H; kc += 4){
      HSTEP2(kc, acc0) HSTEP2(kc + 1, acc1) HSTEP2(kc + 2, acc2) HSTEP2(kc + 3, acc3)
    }
    f32x4 acc = (acc0 + acc1) + (acc2 + acc3);

    // ---- epilogue: gather f/i/c/o via shfl, gates, stage h/out into LDS ----
    float creg[4] = {cr0, cr1, cr2, cr3};
#pragma unroll
    for (int r = 0; r < 4; r++){
      float v = acc[r] + bias;
      float vF = __shfl(v, srcBase);
      float vI = __shfl(v, srcBase + 4);
      float vC = __shfl(v, srcBase + 8);
      float vO = __shfl(v, srcBase + 12);
      if (g == 0){
        int b = (w << 4) | (kg << 2) | r;
        float ft = fast_sigmoid(vF);
        float it = fast_sigmoid(vI);
        float gt = fast_tanh(vC);
        float ot = fast_sigmoid(vO);
        float cn = ft * creg[r] + it * gt;
        creg[r] = cn;
        float hn = ot * fast_tanh(cn);
        int si = (b << 2) | (lc & 3);
        stage_h[si] = f2bf(hn);
        stage_o[si] = hn;
      }
    }
    cr0 = creg[0]; cr1 = creg[1]; cr2 = creg[2]; cr3 = creg[3];

    __syncthreads();   // B: staging visible to wave 0

    // ---- wave 0: coalesced publish (ring sc0sc1 + out plain), drain, add ----
    if (w == 0){
      u32x2  hv2 = *(const u32x2*)&stage_h[lane << 2];   // 8B = one row's 4 cols
      f32x4  ov  = *(const f32x4*)&stage_o[lane << 2];
      *(float4*)(out_t + lane * DL + (bk << 2)) = *(const float4*)&ov;
      unsigned short* hdst = hWr + lane * DL + (bk << 2);
      asm volatile("global_store_dwordx2 %0, %1, off sc0 sc1"
                   :: "v"(hdst), "v"(hv2) : "memory");
      asm volatile("s_waitcnt vmcnt(0)" ::: "memory");
      __builtin_amdgcn_sched_barrier(0);
      if (tid == 0)
        __hip_atomic_fetch_add(myCtr, 1u, __ATOMIC_RELAXED, __HIP_MEMORY_SCOPE_AGENT);
    }

    // ---- overlap: x-part MFMAs for step t+1 (xe independent of h) ----
    acc0 = (f32x4){0.f,0.f,0.f,0.f}; acc1 = (f32x4){0.f,0.f,0.f,0.f};
    acc2 = (f32x4){0.f,0.f,0.f,0.f}; acc3 = (f32x4){0.f,0.f,0.f,0.f};
    if (t + 1 < T_STEPS){
      const unsigned short* xRow = xe + (size_t)(t + 1) * BATCH * DI + xOff;
#pragma unroll
      for (int kc = 0; kc < 16; kc += 4){
        XSTEP(kc, acc0) XSTEP(kc + 1, acc1) XSTEP(kc + 2, acc2) XSTEP(kc + 3, acc3)
      }
    }
  }
#undef XSTEP
#undef HSTEP2
#undef LOADHC
#undef LOADHU
}

extern "C" void kernel_launch(void* const* d_in, const int* in_sizes, int n_in,
                              void* d_out, int out_size, void* d_ws, size_t ws_size,
                              hipStream_t stream){
  const int*   X   = (const int*)d_in[0];
  const float* h0  = (const float*)d_in[1];
  const float* emb = (const float*)d_in[2];
  const float* Wf  = (const float*)d_in[3];
  const float* bf_ = (const float*)d_in[4];
  const float* Wi  = (const float*)d_in[5];
  const float* bi_ = (const float*)d_in[6];
  const float* Wc  = (const float*)d_in[7];
  const float* bc_ = (const float*)d_in[8];
  const float* Wo  = (const float*)d_in[9];
  const float* bo_ = (const float*)d_in[10];
  float* out = (float*)d_out;

  const size_t SLOT = (size_t)BATCH * DL;            // ring slot elems (bf16)
  const size_t base_need =
      sizeof(unsigned short) * ((size_t)T_STEPS * BATCH * DI        // xe
                              + (size_t)256 * NKC * 512             // W_hi
                              + (size_t)256 * NKC_H * 512)          // W_lo
    + sizeof(float) * 4096                                           // bias
    + sizeof(unsigned int) * 8 * FPAD + 4096;                        // bar + slack
  const size_t ring_full = sizeof(unsigned short) * SLOT * (size_t)(T_STEPS + 1);
  const bool cached = ws_size >= base_need + ring_full;
  const size_t ring_elems = cached ? SLOT * (size_t)(T_STEPS + 1) : SLOT * 2;

  char* ws = (char*)d_ws;
  size_t off = 0;
  auto alloc = [&](size_t bytes) -> void* {
    void* p = ws + off;
    off = (off + bytes + 255) & ~((size_t)255);
    return p;
  };
  unsigned short* xe        = (unsigned short*)alloc(sizeof(unsigned short) * (size_t)T_STEPS * BATCH * DI);
  unsigned short* W_hi      = (unsigned short*)alloc(sizeof(unsigned short) * (size_t)256 * NKC * 512);
  unsigned short* W_lo      = (unsigned short*)alloc(sizeof(unsigned short) * (size_t)256 * NKC_H * 512);
  unsigned short* hRing     = (unsigned short*)alloc(sizeof(unsigned short) * ring_elems);
  float*          bias_pack = (float*)alloc(sizeof(float) * 4096);
  unsigned int*   bar       = (unsigned int*)alloc(sizeof(unsigned int) * 8 * FPAD);
  (void)in_sizes; (void)n_in; (void)out_size;

  static bool attr_set = false;
  if (!attr_set){
    hipFuncSetAttribute((const void*)lstm_persist<true>,
                        hipFuncAttributeMaxDynamicSharedMemorySize, 160 * 1024);
    hipFuncSetAttribute((const void*)lstm_persist<false>,
                        hipFuncAttributeMaxDynamicSharedMemorySize, 160 * 1024);
    attr_set = true;
  }

  hipLaunchKernelGGL(prep_xe, dim3(8192), dim3(256), 0, stream, X, emb, xe);
  hipLaunchKernelGGL(prep_w,  dim3(3072), dim3(256), 0, stream, Wf, Wi, Wc, Wo, W_hi, W_lo);
  hipLaunchKernelGGL(prep_h,  dim3(256),  dim3(256), 0, stream, h0, bf_, bi_, bc_, bo_,
                     hRing, bias_pack, bar);
  if (cached)
    hipLaunchKernelGGL((lstm_persist<true>),  dim3(NBLK), dim3(NTHR), 80 * 1024, stream,
                       xe, W_hi, W_lo, hRing, bias_pack, out, bar);
  else
    hipLaunchKernelGGL((lstm_persist<false>), dim3(NBLK), dim3(NTHR), 80 * 1024, stream,
                       xe, W_hi, W_lo, hRing, bias_pack, out, bar);
}